// Round 1
// baseline (1896.667 us; speedup 1.0000x reference)
//
#include <hip/hip_runtime.h>
#include <math.h>

// ---------------- problem constants ----------------
#define S 64            // tokens per window (8x8)
#define D 256           // model dim
#define HEADS 8
#define DH 32
#define NWIN 2048       // 8 * 16 * 16 windows
#define XS_STRIDE 260   // 256 + 4 pad (float4-aligned, bank-spread)
#define QK_STRIDE 36    // 32 + 4 pad
#define P_STRIDE 68     // 64 + 4 pad
#define ATTN_SCALE 0.17677669529663687f   // 32^-0.5

__device__ __forceinline__ float wave_sum64(float v) {
#pragma unroll
  for (int m = 1; m < 64; m <<= 1) v += __shfl_xor(v, m, 64);
  return v;
}

// ---------------- dynamic position bias MLP ----------------
// one wave per relative offset (289 of them); lane = hidden unit (64)
__global__ void dpb_kernel(const float* __restrict__ w1, const float* __restrict__ b1,
                           const float* __restrict__ g1, const float* __restrict__ bb1,
                           const float* __restrict__ w2, const float* __restrict__ b2,
                           const float* __restrict__ g2, const float* __restrict__ bb2,
                           const float* __restrict__ w3, const float* __restrict__ b3,
                           const float* __restrict__ g3, const float* __restrict__ bb3,
                           const float* __restrict__ w4, const float* __restrict__ b4,
                           float* __restrict__ biases) {
  const int r = blockIdx.x;          // 0..288
  const int lane = threadIdx.x;      // 0..63
  const float rel0 = (float)(r / 17 - 8);
  const float rel1 = (float)(r % 17 - 8);

  // layer 1: rel(2) @ w1(2x64) + b1
  float h = rel0 * w1[lane] + rel1 * w1[64 + lane] + b1[lane];
  {
    const float mean = wave_sum64(h) * (1.f / 64.f);
    const float d = h - mean;
    const float var = wave_sum64(d * d) * (1.f / 64.f);
    h = fmaxf(d * rsqrtf(var + 1e-3f) * g1[lane] + bb1[lane], 0.f);
  }
  // layer 2
  float h2 = b2[lane];
  for (int i = 0; i < 64; ++i) h2 += __shfl(h, i, 64) * w2[i * 64 + lane];
  {
    const float mean = wave_sum64(h2) * (1.f / 64.f);
    const float d = h2 - mean;
    const float var = wave_sum64(d * d) * (1.f / 64.f);
    h2 = fmaxf(d * rsqrtf(var + 1e-3f) * g2[lane] + bb2[lane], 0.f);
  }
  // layer 3
  float h3 = b3[lane];
  for (int i = 0; i < 64; ++i) h3 += __shfl(h2, i, 64) * w3[i * 64 + lane];
  {
    const float mean = wave_sum64(h3) * (1.f / 64.f);
    const float d = h3 - mean;
    const float var = wave_sum64(d * d) * (1.f / 64.f);
    h3 = fmaxf(d * rsqrtf(var + 1e-3f) * g3[lane] + bb3[lane], 0.f);
  }
  // layer 4: (64) @ w4(64x1) + b4
  float p = h3 * w4[lane];
  p = wave_sum64(p);
  if (lane == 0) biases[r] = p + b4[0];
}

// ---------------- fused LN + windowed attention + out-proj ----------------
// one block per window; 512 threads (8 waves)
__global__ __launch_bounds__(512, 1) void attn_kernel(
    const float* __restrict__ x, const float* __restrict__ ng,
    const float* __restrict__ nbv, const float* __restrict__ wqkv,
    const float* __restrict__ wout, const float* __restrict__ bout,
    const float* __restrict__ biases, float* __restrict__ out) {
  __shared__ __align__(16) float xs[S * XS_STRIDE];        // LN'd window, 65 KiB
  __shared__ __align__(16) float uqk[2 * S * QK_STRIDE];   // qh|kh, overlaid by P[64][68]
  __shared__ __align__(16) float vhs[S * QK_STRIDE];
  __shared__ __align__(16) float ohs[S * QK_STRIDE];
  __shared__ __align__(16) float bias_s[292];

  float* qh = uqk;
  float* kh = uqk + S * QK_STRIDE;
  float* ps = uqk;  // P matrix, stride P_STRIDE (64*68=4352 <= 4608 floats)

  const int tid = threadIdx.x;
  const int wi = blockIdx.x;
  const int b = wi >> 8;
  const int hb = (wi >> 4) & 15;
  const int wb = wi & 15;

  if (tid < 289) bias_s[tid] = biases[tid];

  // ---- phase 1: LayerNorm (eps 1e-5) into LDS ----
  {
    const int t = tid >> 3;        // token 0..63
    const int d0 = (tid & 7) * 32; // 32 channels per thread
    const int row = hb * 8 + (t >> 3);
    const int col = wb * 8 + (t & 7);
    const float* gp = x + ((((size_t)b * 128 + row) * 128 + col) * 256 + d0);
    float4 v[8];
    float sum = 0.f, ssq = 0.f;
#pragma unroll
    for (int j = 0; j < 8; ++j) {
      v[j] = *(const float4*)(gp + j * 4);
      sum += v[j].x + v[j].y + v[j].z + v[j].w;
      ssq += v[j].x * v[j].x + v[j].y * v[j].y + v[j].z * v[j].z + v[j].w * v[j].w;
    }
#pragma unroll
    for (int m = 1; m < 8; m <<= 1) {
      sum += __shfl_xor(sum, m, 64);
      ssq += __shfl_xor(ssq, m, 64);
    }
    const float mean = sum * (1.f / 256.f);
    const float var = ssq * (1.f / 256.f) - mean * mean;
    const float rstd = rsqrtf(var + 1e-5f);
#pragma unroll
    for (int j = 0; j < 8; ++j) {
      const float4 g4 = *(const float4*)(ng + d0 + j * 4);
      const float4 b4 = *(const float4*)(nbv + d0 + j * 4);
      float4 o;
      o.x = (v[j].x - mean) * rstd * g4.x + b4.x;
      o.y = (v[j].y - mean) * rstd * g4.y + b4.y;
      o.z = (v[j].z - mean) * rstd * g4.z + b4.z;
      o.w = (v[j].w - mean) * rstd * g4.w + b4.w;
      *(float4*)&xs[t * XS_STRIDE + d0 + j * 4] = o;
    }
  }

  // persistent out-projection accumulators: 4 rows x 8 cols per thread
  const int cg = tid & 31;  // cols cg*8 .. cg*8+7
  const int rg = tid >> 5;  // rows rg*4 .. rg*4+3
  float outa[4][8];
#pragma unroll
  for (int i = 0; i < 4; ++i)
#pragma unroll
    for (int j = 0; j < 8; ++j) outa[i][j] = 0.f;

  __syncthreads();

  for (int h = 0; h < HEADS; ++h) {
    // ---- 2a: QKV projection for head h ----
    {
      const int c = tid & 31;
      const int t0 = (tid >> 5) * 4;  // 4 tokens per thread
      const float* wq = wqkv + h * 32 + c;
      const float* wk = wq + 256;
      const float* wv = wq + 512;
      float aq[4] = {0, 0, 0, 0}, ak[4] = {0, 0, 0, 0}, av[4] = {0, 0, 0, 0};
      for (int d = 0; d < 256; d += 4) {
        const float wq0 = wq[(d + 0) * 768], wq1 = wq[(d + 1) * 768];
        const float wq2 = wq[(d + 2) * 768], wq3 = wq[(d + 3) * 768];
        const float wk0 = wk[(d + 0) * 768], wk1 = wk[(d + 1) * 768];
        const float wk2 = wk[(d + 2) * 768], wk3 = wk[(d + 3) * 768];
        const float wv0 = wv[(d + 0) * 768], wv1 = wv[(d + 1) * 768];
        const float wv2 = wv[(d + 2) * 768], wv3 = wv[(d + 3) * 768];
#pragma unroll
        for (int i = 0; i < 4; ++i) {
          const float4 xv = *(const float4*)&xs[(t0 + i) * XS_STRIDE + d];
          aq[i] = fmaf(xv.x, wq0, aq[i]); aq[i] = fmaf(xv.y, wq1, aq[i]);
          aq[i] = fmaf(xv.z, wq2, aq[i]); aq[i] = fmaf(xv.w, wq3, aq[i]);
          ak[i] = fmaf(xv.x, wk0, ak[i]); ak[i] = fmaf(xv.y, wk1, ak[i]);
          ak[i] = fmaf(xv.z, wk2, ak[i]); ak[i] = fmaf(xv.w, wk3, ak[i]);
          av[i] = fmaf(xv.x, wv0, av[i]); av[i] = fmaf(xv.y, wv1, av[i]);
          av[i] = fmaf(xv.z, wv2, av[i]); av[i] = fmaf(xv.w, wv3, av[i]);
        }
      }
#pragma unroll
      for (int i = 0; i < 4; ++i) {
        qh[(t0 + i) * QK_STRIDE + c] = aq[i] * ATTN_SCALE;
        kh[(t0 + i) * QK_STRIDE + c] = ak[i];
        vhs[(t0 + i) * QK_STRIDE + c] = av[i];
      }
    }
    __syncthreads();

    // ---- 2b: sim = q k^T + bias, softmax (row i lives across 64 lanes of wave i/8) ----
    {
      const int j = tid & 63;
      const int iw = tid >> 6;  // wave 0..7 -> rows iw*8..iw*8+7
      float sr[8];
#pragma unroll
      for (int r = 0; r < 8; ++r) sr[r] = 0.f;
      for (int k = 0; k < 32; k += 4) {
        const float4 kv = *(const float4*)&kh[j * QK_STRIDE + k];
#pragma unroll
        for (int r = 0; r < 8; ++r) {
          const float4 qv = *(const float4*)&qh[(iw * 8 + r) * QK_STRIDE + k];
          sr[r] += qv.x * kv.x + qv.y * kv.y + qv.z * kv.z + qv.w * kv.w;
        }
      }
      const int j1 = j >> 3, j2 = j & 7;
#pragma unroll
      for (int r = 0; r < 8; ++r) {
        const int i = iw * 8 + r;
        const int idx = ((i >> 3) - j1 + 7) * 15 + ((i & 7) - j2 + 7);
        sr[r] += bias_s[idx];
      }
#pragma unroll
      for (int r = 0; r < 8; ++r) {
        float m = sr[r];
#pragma unroll
        for (int mm = 32; mm >= 1; mm >>= 1) m = fmaxf(m, __shfl_xor(m, mm, 64));
        const float e = __expf(sr[r] - m);
        float ssum = e;
#pragma unroll
        for (int mm = 32; mm >= 1; mm >>= 1) ssum += __shfl_xor(ssum, mm, 64);
        sr[r] = e / ssum;
      }
      __syncthreads();  // all q/k reads done; safe to overwrite with P
#pragma unroll
      for (int r = 0; r < 8; ++r) ps[(iw * 8 + r) * P_STRIDE + j] = sr[r];
    }
    __syncthreads();

    // ---- 2c: out_h = P @ v ----
    {
      const int k = tid & 31;
      const int i0 = (tid >> 5) * 4;
      float o[4] = {0, 0, 0, 0};
      for (int jc = 0; jc < 64; jc += 4) {
        const float vv0 = vhs[(jc + 0) * QK_STRIDE + k];
        const float vv1 = vhs[(jc + 1) * QK_STRIDE + k];
        const float vv2 = vhs[(jc + 2) * QK_STRIDE + k];
        const float vv3 = vhs[(jc + 3) * QK_STRIDE + k];
#pragma unroll
        for (int ii = 0; ii < 4; ++ii) {
          const float4 pv = *(const float4*)&ps[(i0 + ii) * P_STRIDE + jc];
          o[ii] += pv.x * vv0 + pv.y * vv1 + pv.z * vv2 + pv.w * vv3;
        }
      }
#pragma unroll
      for (int ii = 0; ii < 4; ++ii) ohs[(i0 + ii) * QK_STRIDE + k] = o[ii];
    }
    __syncthreads();

    // ---- 2d: accumulate out-projection for this head's 32 channels ----
    {
      const int c0 = cg * 8;
      for (int k = 0; k < 32; k += 4) {
        float4 a[4];
#pragma unroll
        for (int ii = 0; ii < 4; ++ii)
          a[ii] = *(const float4*)&ohs[(rg * 4 + ii) * QK_STRIDE + k];
#pragma unroll
        for (int kk = 0; kk < 4; ++kk) {
          const float* wr = wout + (h * 32 + k + kk) * 256 + c0;
          const float4 w0 = *(const float4*)wr;
          const float4 w1 = *(const float4*)(wr + 4);
#pragma unroll
          for (int ii = 0; ii < 4; ++ii) {
            const float avv = (kk == 0) ? a[ii].x : (kk == 1) ? a[ii].y
                              : (kk == 2) ? a[ii].z : a[ii].w;
            outa[ii][0] = fmaf(avv, w0.x, outa[ii][0]);
            outa[ii][1] = fmaf(avv, w0.y, outa[ii][1]);
            outa[ii][2] = fmaf(avv, w0.z, outa[ii][2]);
            outa[ii][3] = fmaf(avv, w0.w, outa[ii][3]);
            outa[ii][4] = fmaf(avv, w1.x, outa[ii][4]);
            outa[ii][5] = fmaf(avv, w1.y, outa[ii][5]);
            outa[ii][6] = fmaf(avv, w1.z, outa[ii][6]);
            outa[ii][7] = fmaf(avv, w1.w, outa[ii][7]);
          }
        }
      }
    }
    __syncthreads();  // protect ohs / ps / vhs before next head overwrites
  }

  // ---- epilogue: + b_out, un-window, store ----
  {
    const int c0 = cg * 8;
    const float4 bo0 = *(const float4*)(bout + c0);
    const float4 bo1 = *(const float4*)(bout + c0 + 4);
#pragma unroll
    for (int ii = 0; ii < 4; ++ii) {
      const int s = rg * 4 + ii;
      const int row = hb * 8 + (s >> 3);
      const int col = wb * 8 + (s & 7);
      float* op = out + ((((size_t)b * 128 + row) * 128 + col) * 256 + c0);
      float4 r0, r1;
      r0.x = outa[ii][0] + bo0.x; r0.y = outa[ii][1] + bo0.y;
      r0.z = outa[ii][2] + bo0.z; r0.w = outa[ii][3] + bo0.w;
      r1.x = outa[ii][4] + bo1.x; r1.y = outa[ii][5] + bo1.y;
      r1.z = outa[ii][6] + bo1.z; r1.w = outa[ii][7] + bo1.w;
      *(float4*)op = r0;
      *(float4*)(op + 4) = r1;
    }
  }
}

extern "C" void kernel_launch(void* const* d_in, const int* in_sizes, int n_in,
                              void* d_out, int out_size, void* d_ws, size_t ws_size,
                              hipStream_t stream) {
  const float* x    = (const float*)d_in[0];
  const float* ng   = (const float*)d_in[1];
  const float* nb   = (const float*)d_in[2];
  const float* wqkv = (const float*)d_in[3];
  const float* wout = (const float*)d_in[4];
  const float* bout = (const float*)d_in[5];
  const float* dw1  = (const float*)d_in[6];
  const float* db1  = (const float*)d_in[7];
  const float* dg1  = (const float*)d_in[8];
  const float* dbb1 = (const float*)d_in[9];
  const float* dw2  = (const float*)d_in[10];
  const float* db2  = (const float*)d_in[11];
  const float* dg2  = (const float*)d_in[12];
  const float* dbb2 = (const float*)d_in[13];
  const float* dw3  = (const float*)d_in[14];
  const float* db3  = (const float*)d_in[15];
  const float* dg3  = (const float*)d_in[16];
  const float* dbb3 = (const float*)d_in[17];
  const float* dw4  = (const float*)d_in[18];
  const float* db4  = (const float*)d_in[19];

  float* biases = (float*)d_ws;  // 289 floats of scratch
  float* out = (float*)d_out;

  dpb_kernel<<<289, 64, 0, stream>>>(dw1, db1, dg1, dbb1, dw2, db2, dg2, dbb2,
                                     dw3, db3, dg3, dbb3, dw4, db4, biases);
  attn_kernel<<<NWIN, 512, 0, stream>>>(x, ng, nb, wqkv, wout, bout, biases, out);
}

// Round 3
// 1340.499 us; speedup vs baseline: 1.4149x; 1.4149x over previous
//
#include <hip/hip_runtime.h>
#include <math.h>

#define ATTN_SCALE 0.17677669529663687f   // 32^-0.5
#define XH_STRIDE 264   // 256 + 8 fp16: 528B row = 16B-aligned, 4-bank row skew
#define QO_STRIDE 56    // 32/64-col tiles: 112B row, 28-dword skew -> 2-way max
#define PV_STRIDE 72    // 144B row, 4-dword skew -> 2-way max

typedef __attribute__((ext_vector_type(8))) _Float16 f16x8;
typedef __attribute__((ext_vector_type(4))) float f32x4;

__device__ __forceinline__ f32x4 mfma16(f16x8 a, f16x8 b, f32x4 c) {
  return __builtin_amdgcn_mfma_f32_16x16x32_f16(a, b, c, 0, 0, 0);
}

__device__ __forceinline__ float wave_sum64(float v) {
#pragma unroll
  for (int m = 1; m < 64; m <<= 1) v += __shfl_xor(v, m, 64);
  return v;
}

// ---------------- dynamic position bias MLP ----------------
__global__ void dpb_kernel(const float* __restrict__ w1, const float* __restrict__ b1,
                           const float* __restrict__ g1, const float* __restrict__ bb1,
                           const float* __restrict__ w2, const float* __restrict__ b2,
                           const float* __restrict__ g2, const float* __restrict__ bb2,
                           const float* __restrict__ w3, const float* __restrict__ b3,
                           const float* __restrict__ g3, const float* __restrict__ bb3,
                           const float* __restrict__ w4, const float* __restrict__ b4,
                           float* __restrict__ biases) {
  const int r = blockIdx.x;
  const int lane = threadIdx.x;
  const float rel0 = (float)(r / 17 - 8);
  const float rel1 = (float)(r % 17 - 8);

  float h = rel0 * w1[lane] + rel1 * w1[64 + lane] + b1[lane];
  {
    const float mean = wave_sum64(h) * (1.f / 64.f);
    const float d = h - mean;
    const float var = wave_sum64(d * d) * (1.f / 64.f);
    h = fmaxf(d * rsqrtf(var + 1e-3f) * g1[lane] + bb1[lane], 0.f);
  }
  float h2 = b2[lane];
  for (int i = 0; i < 64; ++i) h2 += __shfl(h, i, 64) * w2[i * 64 + lane];
  {
    const float mean = wave_sum64(h2) * (1.f / 64.f);
    const float d = h2 - mean;
    const float var = wave_sum64(d * d) * (1.f / 64.f);
    h2 = fmaxf(d * rsqrtf(var + 1e-3f) * g2[lane] + bb2[lane], 0.f);
  }
  float h3 = b3[lane];
  for (int i = 0; i < 64; ++i) h3 += __shfl(h2, i, 64) * w3[i * 64 + lane];
  {
    const float mean = wave_sum64(h3) * (1.f / 64.f);
    const float d = h3 - mean;
    const float var = wave_sum64(d * d) * (1.f / 64.f);
    h3 = fmaxf(d * rsqrtf(var + 1e-3f) * g3[lane] + bb3[lane], 0.f);
  }
  float p = wave_sum64(h3 * w4[lane]);
  if (lane == 0) biases[r] = p + b4[0];
}

// ---------------- weight prep: transpose + fp16 hi/lo split ----------------
// wqkv[256][768] -> wt[768][256] (Q columns pre-scaled by ATTN_SCALE)
__global__ void prep_wqkv(const float* __restrict__ w, _Float16* __restrict__ th,
                          _Float16* __restrict__ tl) {
  const int o = blockIdx.x;    // 0..767 (output col)
  const int k = threadIdx.x;   // 0..255 (input dim)
  float v = w[k * 768 + o];
  if (o < 256) v *= ATTN_SCALE;
  const _Float16 hi = (_Float16)v;
  th[o * 256 + k] = hi;
  tl[o * 256 + k] = (_Float16)(v - (float)hi);
}

// wout[256][256] -> wt[256][256]
__global__ void prep_wout(const float* __restrict__ w, _Float16* __restrict__ th,
                          _Float16* __restrict__ tl) {
  const int o = blockIdx.x;
  const int k = threadIdx.x;
  const float v = w[k * 256 + o];
  const _Float16 hi = (_Float16)v;
  th[o * 256 + k] = hi;
  tl[o * 256 + k] = (_Float16)(v - (float)hi);
}

// ---------------- fused LN + windowed attention + out-proj (MFMA) ----------------
// 1 window/block, 512 threads = 8 waves. LDS ~55 KB -> 2 blocks/CU.
__global__ __launch_bounds__(512, 4) void attn_mfma(
    const float* __restrict__ x, const float* __restrict__ gamma,
    const float* __restrict__ beta,
    const _Float16* __restrict__ wqh, const _Float16* __restrict__ wql,
    const _Float16* __restrict__ woh, const _Float16* __restrict__ wol,
    const float* __restrict__ bout, const float* __restrict__ biases,
    float* __restrict__ out) {
  __shared__ __align__(16) _Float16 xh[64 * XH_STRIDE];   // LN'd x, fp16
  __shared__ __align__(16) _Float16 u0[64 * PV_STRIDE];   // Qs(stride 56) / Ps(stride 72)
  __shared__ __align__(16) _Float16 u1[64 * QO_STRIDE];   // Ks / Os
  __shared__ __align__(16) _Float16 Vt[32 * PV_STRIDE];   // V transposed [dh][token]

  const int tid = threadIdx.x;
  const int lane = tid & 63;
  const int w = tid >> 6;        // wave 0..7
  const int l15 = lane & 15;
  const int khi = lane >> 4;     // 0..3
  const int m = w & 3;           // row (token) tile
  const int ngr = w >> 2;        // 0..1 col-group

  const int wi = blockIdx.x;
  const int bb_ = wi >> 8;
  const int hb = (wi >> 4) & 15;
  const int wb = wi & 15;

  // ---- LN (eps 1e-5) -> xh fp16 ----
  {
    const int t = tid >> 3;
    const int d0 = (tid & 7) * 32;
    const int row = hb * 8 + (t >> 3);
    const int col = wb * 8 + (t & 7);
    const float* gp = x + ((((size_t)bb_ * 128 + row) * 128 + col) * 256 + d0);
    float vv[32];
    float sum = 0.f, ssq = 0.f;
#pragma unroll
    for (int j = 0; j < 8; ++j) {
      const float4 v4 = *(const float4*)(gp + j * 4);
      vv[j * 4 + 0] = v4.x; vv[j * 4 + 1] = v4.y;
      vv[j * 4 + 2] = v4.z; vv[j * 4 + 3] = v4.w;
      sum += v4.x + v4.y + v4.z + v4.w;
      ssq += v4.x * v4.x + v4.y * v4.y + v4.z * v4.z + v4.w * v4.w;
    }
#pragma unroll
    for (int mm = 1; mm < 8; mm <<= 1) {
      sum += __shfl_xor(sum, mm, 64);
      ssq += __shfl_xor(ssq, mm, 64);
    }
    const float mean = sum * (1.f / 256.f);
    const float var = ssq * (1.f / 256.f) - mean * mean;
    const float rstd = rsqrtf(var + 1e-5f);
#pragma unroll
    for (int q = 0; q < 8; ++q) {
      const float4 g4 = *(const float4*)(gamma + d0 + q * 4);
      const float4 b4 = *(const float4*)(beta + d0 + q * 4);
      vv[q * 4 + 0] = (vv[q * 4 + 0] - mean) * rstd * g4.x + b4.x;
      vv[q * 4 + 1] = (vv[q * 4 + 1] - mean) * rstd * g4.y + b4.y;
      vv[q * 4 + 2] = (vv[q * 4 + 2] - mean) * rstd * g4.z + b4.z;
      vv[q * 4 + 3] = (vv[q * 4 + 3] - mean) * rstd * g4.w + b4.w;
    }
#pragma unroll
    for (int q = 0; q < 4; ++q) {
      f16x8 pk;
#pragma unroll
      for (int e = 0; e < 8; ++e) pk[e] = (_Float16)vv[q * 8 + e];
      *(f16x8*)&xh[t * XH_STRIDE + d0 + q * 8] = pk;
    }
  }

  // per-lane constants (fixed across heads)
  float bias_r[16];
  if (w < 4) {
#pragma unroll
    for (int nt = 0; nt < 4; ++nt)
#pragma unroll
      for (int rg = 0; rg < 4; ++rg) {
        const int r = w * 16 + khi * 4 + rg;
        const int c = nt * 16 + l15;
        const int idx = ((r >> 3) - (c >> 3) + 7) * 15 + ((r & 7) - (c & 7) + 7);
        bias_r[nt * 4 + rg] = biases[idx];
      }
  }
  float bout_r[8];
#pragma unroll
  for (int t2 = 0; t2 < 8; ++t2) bout_r[t2] = bout[(ngr * 8 + t2) * 16 + l15];

  f32x4 yacc[8];
#pragma unroll
  for (int t2 = 0; t2 < 8; ++t2) yacc[t2] = (f32x4){0.f, 0.f, 0.f, 0.f};

  __syncthreads();

  for (int h = 0; h < 8; ++h) {
    // ---- A: QKV projection (split-W: 2 MFMA/tile), wave owns 3 of 6 col-tiles ----
    f32x4 qkvacc[3];
    int obase[3];
#pragma unroll
    for (int jj = 0; jj < 3; ++jj) {
      qkvacc[jj] = (f32x4){0.f, 0.f, 0.f, 0.f};
      const int j = ngr * 3 + jj;  // 0,1=Q  2,3=K  4,5=V (16 cols each)
      obase[jj] = ((j >> 1) * 256 + h * 32 + (j & 1) * 16 + l15) * 256;
    }
    const int arow = (m * 16 + l15) * XH_STRIDE;
#pragma unroll
    for (int kk = 0; kk < 8; ++kk) {
      const int ko = kk * 32 + khi * 8;
      const f16x8 a = *(const f16x8*)&xh[arow + ko];
#pragma unroll
      for (int jj = 0; jj < 3; ++jj) {
        const f16x8 bh = *(const f16x8*)&wqh[obase[jj] + ko];
        const f16x8 bl = *(const f16x8*)&wql[obase[jj] + ko];
        qkvacc[jj] = mfma16(a, bh, qkvacc[jj]);
        qkvacc[jj] = mfma16(a, bl, qkvacc[jj]);
      }
    }
#pragma unroll
    for (int jj = 0; jj < 3; ++jj) {
      const int j = ngr * 3 + jj;
#pragma unroll
      for (int rg = 0; rg < 4; ++rg) {
        const _Float16 hv = (_Float16)qkvacc[jj][rg];
        const int token = m * 16 + khi * 4 + rg;
        if (j < 2)      u0[token * QO_STRIDE + j * 16 + l15] = hv;           // Q
        else if (j < 4) u1[token * QO_STRIDE + (j - 2) * 16 + l15] = hv;     // K
        else            Vt[((j - 4) * 16 + l15) * PV_STRIDE + token] = hv;   // V^T
      }
    }
    __syncthreads();

    // ---- B: sim = QK^T (waves 0..3 own 16-row strips; plain f16) ----
    f32x4 s4[4];
#pragma unroll
    for (int nt = 0; nt < 4; ++nt) s4[nt] = (f32x4){0.f, 0.f, 0.f, 0.f};
    if (w < 4) {
      const f16x8 qa = *(const f16x8*)&u0[(w * 16 + l15) * QO_STRIDE + khi * 8];
#pragma unroll
      for (int nt = 0; nt < 4; ++nt) {
        const f16x8 kb = *(const f16x8*)&u1[(nt * 16 + l15) * QO_STRIDE + khi * 8];
        s4[nt] = mfma16(qa, kb, s4[nt]);
      }
    }
    __syncthreads();  // all Q reads done before P overwrites u0
    if (w < 4) {
#pragma unroll
      for (int rg = 0; rg < 4; ++rg) {
        const float v0 = s4[0][rg] + bias_r[0 + rg];
        const float v1 = s4[1][rg] + bias_r[4 + rg];
        const float v2 = s4[2][rg] + bias_r[8 + rg];
        const float v3 = s4[3][rg] + bias_r[12 + rg];
        float mx = fmaxf(fmaxf(v0, v1), fmaxf(v2, v3));
#pragma unroll
        for (int mm = 1; mm < 16; mm <<= 1) mx = fmaxf(mx, __shfl_xor(mx, mm, 64));
        const float e0 = __expf(v0 - mx), e1 = __expf(v1 - mx);
        const float e2 = __expf(v2 - mx), e3 = __expf(v3 - mx);
        float sm = e0 + e1 + e2 + e3;
#pragma unroll
        for (int mm = 1; mm < 16; mm <<= 1) sm += __shfl_xor(sm, mm, 64);
        const float inv = 1.f / sm;
        const int prow = (w * 16 + khi * 4 + rg) * PV_STRIDE;
        u0[prow + 0 + l15] = (_Float16)(e0 * inv);
        u0[prow + 16 + l15] = (_Float16)(e1 * inv);
        u0[prow + 32 + l15] = (_Float16)(e2 * inv);
        u0[prow + 48 + l15] = (_Float16)(e3 * inv);
      }
    }
    __syncthreads();

    // ---- C: out_h = P @ V (8 tiles over 8 waves) ----
    {
      f32x4 oa = (f32x4){0.f, 0.f, 0.f, 0.f};
#pragma unroll
      for (int ks = 0; ks < 2; ++ks) {
        const f16x8 pa = *(const f16x8*)&u0[(m * 16 + l15) * PV_STRIDE + ks * 32 + khi * 8];
        const f16x8 vb = *(const f16x8*)&Vt[(ngr * 16 + l15) * PV_STRIDE + ks * 32 + khi * 8];
        oa = mfma16(pa, vb, oa);
      }
#pragma unroll
      for (int rg = 0; rg < 4; ++rg)
        u1[(m * 16 + khi * 4 + rg) * QO_STRIDE + ngr * 16 + l15] = (_Float16)oa[rg];
    }
    __syncthreads();

    // ---- D: Y += O_h @ Wout_h (split-W), wave owns 8 of 16 col-tiles ----
    {
      const f16x8 ao = *(const f16x8*)&u1[(m * 16 + l15) * QO_STRIDE + khi * 8];
      const int hk = h * 32 + khi * 8;
#pragma unroll
      for (int t2 = 0; t2 < 8; ++t2) {
        const int o = ((ngr * 8 + t2) * 16 + l15) * 256;
        const f16x8 bh = *(const f16x8*)&woh[o + hk];
        const f16x8 bl = *(const f16x8*)&wol[o + hk];
        yacc[t2] = mfma16(ao, bh, yacc[t2]);
        yacc[t2] = mfma16(ao, bl, yacc[t2]);
      }
    }
    __syncthreads();  // protects next head's Q/K/Vt overwrites
  }

  // ---- epilogue: + b_out, un-window, store fp32 ----
#pragma unroll
  for (int t2 = 0; t2 < 8; ++t2) {
#pragma unroll
    for (int rg = 0; rg < 4; ++rg) {
      const int tok = m * 16 + khi * 4 + rg;
      const int row = hb * 8 + (tok >> 3);
      const int col = wb * 8 + (tok & 7);
      out[(((size_t)bb_ * 128 + row) * 128 + col) * 256 + (ngr * 8 + t2) * 16 + l15] =
          yacc[t2][rg] + bout_r[t2];
    }
  }
}

extern "C" void kernel_launch(void* const* d_in, const int* in_sizes, int n_in,
                              void* d_out, int out_size, void* d_ws, size_t ws_size,
                              hipStream_t stream) {
  const float* x    = (const float*)d_in[0];
  const float* ng   = (const float*)d_in[1];
  const float* nb   = (const float*)d_in[2];
  const float* wqkv = (const float*)d_in[3];
  const float* wout = (const float*)d_in[4];
  const float* bout = (const float*)d_in[5];
  const float* dw1  = (const float*)d_in[6];
  const float* db1  = (const float*)d_in[7];
  const float* dg1  = (const float*)d_in[8];
  const float* dbb1 = (const float*)d_in[9];
  const float* dw2  = (const float*)d_in[10];
  const float* db2  = (const float*)d_in[11];
  const float* dg2  = (const float*)d_in[12];
  const float* dbb2 = (const float*)d_in[13];
  const float* dw3  = (const float*)d_in[14];
  const float* db3  = (const float*)d_in[15];
  const float* dg3  = (const float*)d_in[16];
  const float* dbb3 = (const float*)d_in[17];
  const float* dw4  = (const float*)d_in[18];
  const float* db4  = (const float*)d_in[19];

  char* ws = (char*)d_ws;
  float* biases  = (float*)ws;                          //   2048 B (289 used)
  _Float16* wqh  = (_Float16*)(ws + 2048);              // 393216 B
  _Float16* wql  = (_Float16*)(ws + 2048 + 393216);     // 393216 B
  _Float16* woh  = (_Float16*)(ws + 2048 + 786432);     // 131072 B
  _Float16* wol  = (_Float16*)(ws + 2048 + 917504);     // 131072 B -> 1,050,624 B total

  float* out = (float*)d_out;

  dpb_kernel<<<289, 64, 0, stream>>>(dw1, db1, dg1, dbb1, dw2, db2, dg2, dbb2,
                                     dw3, db3, dg3, dbb3, dw4, db4, biases);
  prep_wqkv<<<768, 256, 0, stream>>>(wqkv, wqh, wql);
  prep_wout<<<256, 256, 0, stream>>>(wout, woh, wol);
  attn_mfma<<<2048, 512, 0, stream>>>(x, ng, nb, wqh, wql, woh, wol, bout, biases, out);
}

// Round 6
// 552.578 us; speedup vs baseline: 3.4324x; 2.4259x over previous
//
#include <hip/hip_runtime.h>
#include <math.h>

#define ATTN_SCALE 0.17677669529663687f   // 32^-0.5
#define XH_STRIDE 264   // f16 row stride: 528B = 33*16, 2-way max on frag reads
#define QK_STRIDE 264
#define VT_STRIDE 72    // 144B = 9*16
#define BE_STRIDE 68    // f32 row stride: 272B = 17*16

typedef __attribute__((ext_vector_type(8))) _Float16 f16x8;
typedef __attribute__((ext_vector_type(4))) _Float16 f16x4;
typedef __attribute__((ext_vector_type(4))) float f32x4;

__device__ __forceinline__ f32x4 mfma16(f16x8 a, f16x8 b, f32x4 c) {
  return __builtin_amdgcn_mfma_f32_16x16x32_f16(a, b, c, 0, 0, 0);
}

__device__ __forceinline__ float wave_sum64(float v) {
#pragma unroll
  for (int m = 1; m < 64; m <<= 1) v += __shfl_xor(v, m, 64);
  return v;
}

// ---------------- dynamic position bias MLP ----------------
__global__ void dpb_kernel(const float* __restrict__ w1, const float* __restrict__ b1,
                           const float* __restrict__ g1, const float* __restrict__ bb1,
                           const float* __restrict__ w2, const float* __restrict__ b2,
                           const float* __restrict__ g2, const float* __restrict__ bb2,
                           const float* __restrict__ w3, const float* __restrict__ b3,
                           const float* __restrict__ g3, const float* __restrict__ bb3,
                           const float* __restrict__ w4, const float* __restrict__ b4,
                           float* __restrict__ biases) {
  const int r = blockIdx.x;
  const int lane = threadIdx.x;
  const float rel0 = (float)(r / 17 - 8);
  const float rel1 = (float)(r % 17 - 8);

  float h = rel0 * w1[lane] + rel1 * w1[64 + lane] + b1[lane];
  {
    const float mean = wave_sum64(h) * (1.f / 64.f);
    const float d = h - mean;
    const float var = wave_sum64(d * d) * (1.f / 64.f);
    h = fmaxf(d * rsqrtf(var + 1e-3f) * g1[lane] + bb1[lane], 0.f);
  }
  float h2 = b2[lane];
  for (int i = 0; i < 64; ++i) h2 += __shfl(h, i, 64) * w2[i * 64 + lane];
  {
    const float mean = wave_sum64(h2) * (1.f / 64.f);
    const float d = h2 - mean;
    const float var = wave_sum64(d * d) * (1.f / 64.f);
    h2 = fmaxf(d * rsqrtf(var + 1e-3f) * g2[lane] + bb2[lane], 0.f);
  }
  float h3 = b3[lane];
  for (int i = 0; i < 64; ++i) h3 += __shfl(h2, i, 64) * w3[i * 64 + lane];
  {
    const float mean = wave_sum64(h3) * (1.f / 64.f);
    const float d = h3 - mean;
    const float var = wave_sum64(d * d) * (1.f / 64.f);
    h3 = fmaxf(d * rsqrtf(var + 1e-3f) * g3[lane] + bb3[lane], 0.f);
  }
  float p = wave_sum64(h3 * w4[lane]);
  if (lane == 0) biases[r] = p + b4[0];
}

// ---------------- weight prep: transpose + fp16 hi/lo split ----------------
__global__ void prep_wqkv(const float* __restrict__ w, _Float16* __restrict__ th,
                          _Float16* __restrict__ tl) {
  const int o = blockIdx.x;    // 0..767
  const int k = threadIdx.x;   // 0..255
  float v = w[k * 768 + o];
  if (o < 256) v *= ATTN_SCALE;
  const _Float16 hi = (_Float16)v;
  th[o * 256 + k] = hi;
  tl[o * 256 + k] = (_Float16)(v - (float)hi);
}

__global__ void prep_wout(const float* __restrict__ w, _Float16* __restrict__ th,
                          _Float16* __restrict__ tl) {
  const int o = blockIdx.x;
  const int k = threadIdx.x;
  const float v = w[k * 256 + o];
  const _Float16 hi = (_Float16)v;
  th[o * 256 + k] = hi;
  tl[o * 256 + k] = (_Float16)(v - (float)hi);
}

// ---------------- fused LN + windowed attention + out-proj (MFMA, 3-barrier) ----------------
// 1 window/block, 512 threads = 8 waves, ~152 KB LDS -> 1 block/CU.
__global__ __launch_bounds__(512, 2) void attn_mfma2(
    const float* __restrict__ x, const float* __restrict__ gamma,
    const float* __restrict__ beta,
    const _Float16* __restrict__ wqh, const _Float16* __restrict__ wql,
    const _Float16* __restrict__ woh, const _Float16* __restrict__ wol,
    const float* __restrict__ bout, const float* __restrict__ biases,
    float* __restrict__ out) {
  __shared__ __align__(16) _Float16 xh[64 * XH_STRIDE];   // 33792 B  LN'd x
  __shared__ __align__(16) _Float16 Qs[64 * QK_STRIDE];   // 33792 B  Q (-> P cols 0..31)
  __shared__ __align__(16) _Float16 Ks[64 * QK_STRIDE];   // 33792 B  K (-> P cols 32..63 -> O)
  __shared__ __align__(16) _Float16 Vt[256 * VT_STRIDE];  // 36864 B  V^T [dh_global][token]
  __shared__ __align__(16) float    Bexp[64 * BE_STRIDE]; // 17408 B  bias [qt][kt]

  const int tid = threadIdx.x;
  const int lane = tid & 63;
  const int w = tid >> 6;        // wave 0..7 (= head in phase 2)
  const int l15 = lane & 15;
  const int khi = lane >> 4;     // 0..3

  const int wi = blockIdx.x;
  const int bb_ = wi >> 8;
  const int hb = (wi >> 4) & 15;
  const int wb = wi & 15;

  // ---- LN (eps 1e-5) -> xh fp16 ----
  {
    const int t = tid >> 3;
    const int d0 = (tid & 7) * 32;
    const int row = hb * 8 + (t >> 3);
    const int col = wb * 8 + (t & 7);
    const float* gp = x + ((((size_t)bb_ * 128 + row) * 128 + col) * 256 + d0);
    float vv[32];
    float sum = 0.f, ssq = 0.f;
#pragma unroll
    for (int j = 0; j < 8; ++j) {
      const float4 v4 = *(const float4*)(gp + j * 4);
      vv[j * 4 + 0] = v4.x; vv[j * 4 + 1] = v4.y;
      vv[j * 4 + 2] = v4.z; vv[j * 4 + 3] = v4.w;
      sum += v4.x + v4.y + v4.z + v4.w;
      ssq += v4.x * v4.x + v4.y * v4.y + v4.z * v4.z + v4.w * v4.w;
    }
#pragma unroll
    for (int mm = 1; mm < 8; mm <<= 1) {
      sum += __shfl_xor(sum, mm, 64);
      ssq += __shfl_xor(ssq, mm, 64);
    }
    const float mean = sum * (1.f / 256.f);
    const float var = ssq * (1.f / 256.f) - mean * mean;
    const float rstd = rsqrtf(var + 1e-5f);
#pragma unroll
    for (int q = 0; q < 8; ++q) {
      const float4 g4 = *(const float4*)(gamma + d0 + q * 4);
      const float4 b4 = *(const float4*)(beta + d0 + q * 4);
      vv[q * 4 + 0] = (vv[q * 4 + 0] - mean) * rstd * g4.x + b4.x;
      vv[q * 4 + 1] = (vv[q * 4 + 1] - mean) * rstd * g4.y + b4.y;
      vv[q * 4 + 2] = (vv[q * 4 + 2] - mean) * rstd * g4.z + b4.z;
      vv[q * 4 + 3] = (vv[q * 4 + 3] - mean) * rstd * g4.w + b4.w;
    }
#pragma unroll
    for (int q = 0; q < 4; ++q) {
      f16x8 pk;
#pragma unroll
      for (int e = 0; e < 8; ++e) pk[e] = (_Float16)vv[q * 8 + e];
      *(f16x8*)&xh[t * XH_STRIDE + d0 + q * 8] = pk;
    }
  }

  // ---- expand bias table: Bexp[qt][kt] (4096 entries / 512 threads) ----
#pragma unroll
  for (int j = 0; j < 8; ++j) {
    const int e = tid + 512 * j;
    const int qt = e >> 6, kt = e & 63;
    const int idx = ((qt >> 3) - (kt >> 3) + 7) * 15 + ((qt & 7) - (kt & 7) + 7);
    Bexp[qt * BE_STRIDE + kt] = biases[idx];
  }

  __syncthreads();   // barrier 1: xh + Bexp ready

  // ---- Phase 1: QKV all heads. wave w owns 6 coltiles (96 cols of 768) ----
  {
    f32x4 acc[6][4];
#pragma unroll
    for (int j = 0; j < 6; ++j)
#pragma unroll
      for (int m = 0; m < 4; ++m) acc[j][m] = (f32x4){0.f, 0.f, 0.f, 0.f};

    const int ko0 = khi * 8;
#pragma unroll
    for (int kt = 0; kt < 8; ++kt) {
      const int ko = kt * 32 + ko0;
      f16x8 a0 = *(const f16x8*)&xh[(0 * 16 + l15) * XH_STRIDE + ko];
      f16x8 a1 = *(const f16x8*)&xh[(1 * 16 + l15) * XH_STRIDE + ko];
      f16x8 a2 = *(const f16x8*)&xh[(2 * 16 + l15) * XH_STRIDE + ko];
      f16x8 a3 = *(const f16x8*)&xh[(3 * 16 + l15) * XH_STRIDE + ko];
#pragma unroll
      for (int j = 0; j < 6; ++j) {
        const int wcol = (w * 6 + j) * 16 + l15;          // 0..767
        const int base = wcol * 256 + ko;
        const f16x8 bh = *(const f16x8*)&wqh[base];
        const f16x8 bl = *(const f16x8*)&wql[base];
        acc[j][0] = mfma16(a0, bh, acc[j][0]); acc[j][0] = mfma16(a0, bl, acc[j][0]);
        acc[j][1] = mfma16(a1, bh, acc[j][1]); acc[j][1] = mfma16(a1, bl, acc[j][1]);
        acc[j][2] = mfma16(a2, bh, acc[j][2]); acc[j][2] = mfma16(a2, bl, acc[j][2]);
        acc[j][3] = mfma16(a3, bh, acc[j][3]); acc[j][3] = mfma16(a3, bl, acc[j][3]);
      }
    }

    // store Q / K (scalar b16) and V^T (packed b64)
#pragma unroll
    for (int j = 0; j < 6; ++j) {
      const int wcol = (w * 6 + j) * 16 + l15;
      if (wcol < 256) {
#pragma unroll
        for (int m = 0; m < 4; ++m)
#pragma unroll
          for (int rg = 0; rg < 4; ++rg)
            Qs[(m * 16 + khi * 4 + rg) * QK_STRIDE + wcol] = (_Float16)acc[j][m][rg];
      } else if (wcol < 512) {
#pragma unroll
        for (int m = 0; m < 4; ++m)
#pragma unroll
          for (int rg = 0; rg < 4; ++rg)
            Ks[(m * 16 + khi * 4 + rg) * QK_STRIDE + (wcol - 256)] = (_Float16)acc[j][m][rg];
      } else {
        const int vcol = wcol - 512;
#pragma unroll
        for (int m = 0; m < 4; ++m) {
          f16x4 pv;
#pragma unroll
          for (int rg = 0; rg < 4; ++rg) pv[rg] = (_Float16)acc[j][m][rg];
          *(f16x4*)&Vt[vcol * VT_STRIDE + m * 16 + khi * 4] = pv;
        }
      }
    }
  }

  __syncthreads();   // barrier 2: Q/K/Vt ready

  // ---- Phase 2: wave w handles head h=w end-to-end (no cross-wave sync) ----
  {
    const int h = w;
    const int hoff = h * 32 + khi * 8;

    // simT[kt_tile][qt_tile] = K Q^T (K=32, 1 k-step)
    f16x8 ka[4], qb[4];
#pragma unroll
    for (int mt = 0; mt < 4; ++mt)
      ka[mt] = *(const f16x8*)&Ks[(mt * 16 + l15) * QK_STRIDE + hoff];
#pragma unroll
    for (int nt = 0; nt < 4; ++nt)
      qb[nt] = *(const f16x8*)&Qs[(nt * 16 + l15) * QK_STRIDE + hoff];

    f32x4 st[4][4];
#pragma unroll
    for (int mt = 0; mt < 4; ++mt)
#pragma unroll
      for (int nt = 0; nt < 4; ++nt) {
        st[mt][nt] = (f32x4){0.f, 0.f, 0.f, 0.f};
        st[mt][nt] = mfma16(ka[mt], qb[nt], st[mt][nt]);
      }

    // + bias (vectorized from Bexp[qt][kt])
#pragma unroll
    for (int nt = 0; nt < 4; ++nt) {
      const int qrow = (nt * 16 + l15) * BE_STRIDE;
#pragma unroll
      for (int mt = 0; mt < 4; ++mt) {
        const f32x4 bv = *(const f32x4*)&Bexp[qrow + mt * 16 + khi * 4];
        st[mt][nt] = st[mt][nt] + bv;
      }
    }

    // softmax over ktok (16 in-lane values + khi shuffles), per qt group nt
#pragma unroll
    for (int nt = 0; nt < 4; ++nt) {
      float mx = st[0][nt][0];
#pragma unroll
      for (int mt = 0; mt < 4; ++mt)
#pragma unroll
        for (int rg = 0; rg < 4; ++rg) mx = fmaxf(mx, st[mt][nt][rg]);
      mx = fmaxf(mx, __shfl_xor(mx, 16, 64));
      mx = fmaxf(mx, __shfl_xor(mx, 32, 64));
      float sm = 0.f;
#pragma unroll
      for (int mt = 0; mt < 4; ++mt)
#pragma unroll
        for (int rg = 0; rg < 4; ++rg) {
          const float e = __expf(st[mt][nt][rg] - mx);
          st[mt][nt][rg] = e;
          sm += e;
        }
      sm += __shfl_xor(sm, 16, 64);
      sm += __shfl_xor(sm, 32, 64);
      const float inv = 1.f / sm;
#pragma unroll
      for (int mt = 0; mt < 4; ++mt)
#pragma unroll
        for (int rg = 0; rg < 4; ++rg) st[mt][nt][rg] *= inv;
    }

    // write P (row=qt, col=ktok) into dead Q/K head-slices, packed b64
#pragma unroll
    for (int nt = 0; nt < 4; ++nt) {
      const int qt = nt * 16 + l15;
#pragma unroll
      for (int mt = 0; mt < 4; ++mt) {
        f16x4 pp;
#pragma unroll
        for (int rg = 0; rg < 4; ++rg) pp[rg] = (_Float16)st[mt][nt][rg];
        if (mt < 2)
          *(f16x4*)&Qs[qt * QK_STRIDE + h * 32 + mt * 16 + khi * 4] = pp;
        else
          *(f16x4*)&Ks[qt * QK_STRIDE + h * 32 + (mt - 2) * 16 + khi * 4] = pp;
      }
    }

    // O^T = V^T P^T : A = Vt rows (dh), B = P rows (qt)
    f32x4 ot[2][4];
#pragma unroll
    for (int dt = 0; dt < 2; ++dt)
#pragma unroll
      for (int nn = 0; nn < 4; ++nn) ot[dt][nn] = (f32x4){0.f, 0.f, 0.f, 0.f};

#pragma unroll
    for (int kt2 = 0; kt2 < 2; ++kt2) {
      f16x8 va[2], pb[4];
#pragma unroll
      for (int dt = 0; dt < 2; ++dt)
        va[dt] = *(const f16x8*)&Vt[(h * 32 + dt * 16 + l15) * VT_STRIDE + kt2 * 32 + khi * 8];
#pragma unroll
      for (int nn = 0; nn < 4; ++nn) {
        if (kt2 == 0)
          pb[nn] = *(const f16x8*)&Qs[(nn * 16 + l15) * QK_STRIDE + hoff];
        else
          pb[nn] = *(const f16x8*)&Ks[(nn * 16 + l15) * QK_STRIDE + hoff];
      }
#pragma unroll
      for (int dt = 0; dt < 2; ++dt)
#pragma unroll
        for (int nn = 0; nn < 4; ++nn) ot[dt][nn] = mfma16(va[dt], pb[nn], ot[dt][nn]);
    }

    // O (token-row major) overlays Ks: cols h*32..h*32+32, packed b64
#pragma unroll
    for (int nn = 0; nn < 4; ++nn) {
      const int tok = nn * 16 + l15;
#pragma unroll
      for (int dt = 0; dt < 2; ++dt) {
        f16x4 ov;
#pragma unroll
        for (int rg = 0; rg < 4; ++rg) ov[rg] = (_Float16)ot[dt][nn][rg];
        *(f16x4*)&Ks[tok * QK_STRIDE + h * 32 + dt * 16 + khi * 4] = ov;
      }
    }
  }

  __syncthreads();   // barrier 3: O ready in Ks

  // ---- Phase 3: Y = O @ Wout + b_out. wave w owns coltiles 2w, 2w+1 ----
  {
    f32x4 yacc[2][4];
#pragma unroll
    for (int j = 0; j < 2; ++j)
#pragma unroll
      for (int m = 0; m < 4; ++m) yacc[j][m] = (f32x4){0.f, 0.f, 0.f, 0.f};

    const int ko0 = khi * 8;
#pragma unroll
    for (int kt = 0; kt < 8; ++kt) {
      const int ko = kt * 32 + ko0;
      f16x8 a0 = *(const f16x8*)&Ks[(0 * 16 + l15) * QK_STRIDE + ko];
      f16x8 a1 = *(const f16x8*)&Ks[(1 * 16 + l15) * QK_STRIDE + ko];
      f16x8 a2 = *(const f16x8*)&Ks[(2 * 16 + l15) * QK_STRIDE + ko];
      f16x8 a3 = *(const f16x8*)&Ks[(3 * 16 + l15) * QK_STRIDE + ko];
#pragma unroll
      for (int j = 0; j < 2; ++j) {
        const int oc = (w * 2 + j) * 16 + l15;            // 0..255
        const int base = oc * 256 + ko;
        const f16x8 bh = *(const f16x8*)&woh[base];
        const f16x8 bl = *(const f16x8*)&wol[base];
        yacc[j][0] = mfma16(a0, bh, yacc[j][0]); yacc[j][0] = mfma16(a0, bl, yacc[j][0]);
        yacc[j][1] = mfma16(a1, bh, yacc[j][1]); yacc[j][1] = mfma16(a1, bl, yacc[j][1]);
        yacc[j][2] = mfma16(a2, bh, yacc[j][2]); yacc[j][2] = mfma16(a2, bl, yacc[j][2]);
        yacc[j][3] = mfma16(a3, bh, yacc[j][3]); yacc[j][3] = mfma16(a3, bl, yacc[j][3]);
      }
    }

    // epilogue: + b_out, un-window, store fp32
#pragma unroll
    for (int j = 0; j < 2; ++j) {
      const int oc = (w * 2 + j) * 16 + l15;
      const float bo = bout[oc];
#pragma unroll
      for (int m = 0; m < 4; ++m)
#pragma unroll
        for (int rg = 0; rg < 4; ++rg) {
          const int tok = m * 16 + khi * 4 + rg;
          const int row = hb * 8 + (tok >> 3);
          const int col = wb * 8 + (tok & 7);
          out[(((size_t)bb_ * 128 + row) * 128 + col) * 256 + oc] = yacc[j][m][rg] + bo;
        }
    }
  }
}

extern "C" void kernel_launch(void* const* d_in, const int* in_sizes, int n_in,
                              void* d_out, int out_size, void* d_ws, size_t ws_size,
                              hipStream_t stream) {
  const float* x    = (const float*)d_in[0];
  const float* ng   = (const float*)d_in[1];
  const float* nb   = (const float*)d_in[2];
  const float* wqkv = (const float*)d_in[3];
  const float* wout = (const float*)d_in[4];
  const float* bout = (const float*)d_in[5];
  const float* dw1  = (const float*)d_in[6];
  const float* db1  = (const float*)d_in[7];
  const float* dg1  = (const float*)d_in[8];
  const float* dbb1 = (const float*)d_in[9];
  const float* dw2  = (const float*)d_in[10];
  const float* db2  = (const float*)d_in[11];
  const float* dg2  = (const float*)d_in[12];
  const float* dbb2 = (const float*)d_in[13];
  const float* dw3  = (const float*)d_in[14];
  const float* db3  = (const float*)d_in[15];
  const float* dg3  = (const float*)d_in[16];
  const float* dbb3 = (const float*)d_in[17];
  const float* dw4  = (const float*)d_in[18];
  const float* db4  = (const float*)d_in[19];

  char* ws = (char*)d_ws;
  float* biases  = (float*)ws;                          //   2048 B (289 used)
  _Float16* wqh  = (_Float16*)(ws + 2048);              // 393216 B
  _Float16* wql  = (_Float16*)(ws + 2048 + 393216);     // 393216 B
  _Float16* woh  = (_Float16*)(ws + 2048 + 786432);     // 131072 B
  _Float16* wol  = (_Float16*)(ws + 2048 + 917504);     // 131072 B -> 1,050,624 B total

  float* out = (float*)d_out;

  dpb_kernel<<<289, 64, 0, stream>>>(dw1, db1, dg1, dbb1, dw2, db2, dg2, dbb2,
                                     dw3, db3, dg3, dbb3, dw4, db4, biases);
  prep_wqkv<<<768, 256, 0, stream>>>(wqkv, wqh, wql);
  prep_wout<<<256, 256, 0, stream>>>(wout, woh, wol);
  attn_mfma2<<<2048, 512, 0, stream>>>(x, ng, nb, wqh, wql, woh, wol, bout, biases, out);
}